// Round 8
// baseline (2196.928 us; speedup 1.0000x reference)
//
#include <hip/hip_runtime.h>

// EnhancedQuantumInspiredLSTM on MI355X (gfx950).
// Round-16 = r8/r15 protocol with the B2+gbuf phase ELIMINATED:
//  - B operand packed as (gate,col): B-row = (n15>>2)*512 + c0 + wv*4 + (n15&3)
//    -> each wave holds ALL 4 gates for its 4 columns. After MFMA, gates are
//    gathered with 12 in-wave shuffles (lane+4/8/12); EW runs in-register in
//    owner lanes (n15<4) of EVERY wave. No gbuf, no B2 barrier: 2 barriers/step.
//  - h0 slots 4 -> 8; l0 WAR guard f1>=t-6 (was t-2): never blocks in steady state.
//  - XCD co-location kept from r15: dom=blk&3, role=blk>>2 (FETCH 430->125MB).
//  - flags/slots/poll targets/B1/B3/agent scope otherwise r8-exact.
//  - bounded polls + free-run latch (hang insurance, proven harmless).

typedef _Float16 f16;
typedef _Float16 f16x8 __attribute__((ext_vector_type(8)));
typedef float f32x4 __attribute__((ext_vector_type(4)));
typedef unsigned long long u64;

#define MFMA16(a, b, c) __builtin_amdgcn_mfma_f32_16x16x32_f16((a), (b), (c), 0, 0, 0)
#define LD_AG(p) __hip_atomic_load((p), __ATOMIC_RELAXED, __HIP_MEMORY_SCOPE_AGENT)
#define ST_AG(p, v) __hip_atomic_store((p), (v), __ATOMIC_RELAXED, __HIP_MEMORY_SCOPE_AGENT)
#define POLL_CAP (1 << 20)

// ---- workspace layout (bytes) ----
#define OFF_Q16 0UL           // 33,554,432
#define OFF_X16 33554432UL    // 8,388,608
#define OFF_W16 41943040UL    // 8,388,608  [l][row][k']
#define OFF_COS 50331648UL    // 131,072
#define OFF_SIN 50462720UL    // 131,072
#define OFF_BSUM 50593792UL   // 16,384
#define OFF_HBUF 50610176UL   // h0: 4dom*8slot*16*512*2=524,288 ; h1: 4*2*16*512*2=131,072
#define OFF_HLAST 51265536UL  // 131,072
#define OFF_FC1WT 51396608UL  // 1,048,576
#define OFF_FLG 52445184UL    // 8192 dwords = 32,768
#define WS_NEEDED 52477952UL

// =====================================================================
// prep
// =====================================================================
__global__ __launch_bounds__(256) void k_prep(
    const float* __restrict__ x, const float* __restrict__ theta,
    const float* __restrict__ phi, const float* __restrict__ thn,
    const float* __restrict__ phn, const float* __restrict__ Wih,
    const float* __restrict__ Whh, const float* __restrict__ bih,
    const float* __restrict__ bhh, const float* __restrict__ fc1w,
    f16* __restrict__ x16, f16* __restrict__ w16, f16* __restrict__ cosT,
    f16* __restrict__ sinT, float* __restrict__ bsum, float* __restrict__ fc1wT,
    f16* __restrict__ hbuf, unsigned* __restrict__ flg) {
  const int T1 = 4194304;        // x16
  const int T2 = T1 + 4194304;   // w16 combined [l][2048][1024]
  const int T3 = T2 + 65536;     // cos/sin
  const int T4 = T3 + 262144;    // fc1wT
  const int T5 = T4 + 4096;      // bsum
  const int T6 = T5 + 327680;    // zero hbuf (h0 262144 + h1 65536 f16)
  const int T7 = T6 + 8192;      // zero flags (dwords)
  for (int idx = blockIdx.x * 256 + threadIdx.x; idx < T7; idx += gridDim.x * 256) {
    if (idx < T1) {
      int s = idx >> 13, rem = idx & 8191, b = rem >> 7, i = rem & 127;
      x16[idx] = (f16)x[b * 65536 + s * 128 + i];
    } else if (idx < T2) {
      int j = idx - T1;
      int l = j >> 21, rem = j & 2097151, r = rem >> 10, k = rem & 1023;
      float v = (k < 512) ? Wih[((size_t)l * 2048 + r) * 512 + k]
                          : Whh[((size_t)l * 2048 + r) * 512 + (k - 512)];
      w16[(size_t)l * 2097152 + (size_t)r * 1024 + k] = (f16)v;
    } else if (idx < T3) {
      int e = idx - T2;
      int i = e >> 9, h = e & 511;
      cosT[h * 128 + i] = (f16)cosf(theta[e] + thn[e]);
      sinT[h * 128 + i] = (f16)sinf(phi[e] + phn[e]);
    } else if (idx < T4) {
      int e = idx - T3;
      int n = e >> 9, k = e & 511;
      fc1wT[k * 512 + n] = fc1w[e];
    } else if (idx < T5) {
      int e = idx - T4;
      bsum[e] = bih[e] + bhh[e];
    } else if (idx < T6) {
      hbuf[idx - T5] = (f16)0.f;
    } else {
      flg[idx - T6] = 0u;
    }
  }
}

// =====================================================================
// quantum: q16[(s*64+b)][h] = |x.(cos+isin)|, fp16 MFMA (unchanged)
// =====================================================================
__global__ __launch_bounds__(256) void k_quantum(
    const f16* __restrict__ x16, const f16* __restrict__ cosT,
    const f16* __restrict__ sinT, f16* __restrict__ q16) {
  __shared__ __align__(16) f16 a_lds[64 * 136];
  const int tid = threadIdx.x;
  const int r0 = blockIdx.x * 64, h0 = blockIdx.y * 128;
#pragma unroll
  for (int g = 0; g < 4; ++g) {
    int G = g * 256 + tid, row = G >> 4, col = G & 15;
    *(uint4*)((char*)a_lds + row * 272 + col * 16) =
        *(const uint4*)(x16 + (size_t)(r0 + row) * 128 + col * 8);
  }
  __syncthreads();
  const int wv = tid >> 6, lane = tid & 63, n15 = lane & 15, quad = lane >> 4;
  const int nb = h0 + wv * 32;
  f32x4 ac[4][2], as_[4][2];
#pragma unroll
  for (int mt = 0; mt < 4; ++mt)
#pragma unroll
    for (int nt = 0; nt < 2; ++nt) {
      ac[mt][nt] = (f32x4){0.f, 0.f, 0.f, 0.f};
      as_[mt][nt] = (f32x4){0.f, 0.f, 0.f, 0.f};
    }
#pragma unroll
  for (int it = 0; it < 4; ++it) {
    f16x8 a[4];
#pragma unroll
    for (int mt = 0; mt < 4; ++mt)
      a[mt] = *(const f16x8*)((const char*)a_lds + (mt * 16 + n15) * 272 + it * 64 + quad * 16);
#pragma unroll
    for (int nt = 0; nt < 2; ++nt) {
      const f16x8 bc = *(const f16x8*)(cosT + (size_t)(nb + nt * 16 + n15) * 128 + it * 32 + quad * 8);
      const f16x8 bs = *(const f16x8*)(sinT + (size_t)(nb + nt * 16 + n15) * 128 + it * 32 + quad * 8);
#pragma unroll
      for (int mt = 0; mt < 4; ++mt) {
        ac[mt][nt] = MFMA16(a[mt], bc, ac[mt][nt]);
        as_[mt][nt] = MFMA16(a[mt], bs, as_[mt][nt]);
      }
    }
  }
#pragma unroll
  for (int mt = 0; mt < 4; ++mt)
#pragma unroll
    for (int nt = 0; nt < 2; ++nt)
#pragma unroll
      for (int r = 0; r < 4; ++r) {
        int row = r0 + mt * 16 + quad * 4 + r;
        int col = nb + nt * 16 + n15;
        float re = ac[mt][nt][r], im = as_[mt][nt][r];
        q16[(size_t)row * 512 + col] = (f16)sqrtf(re * re + im * im);
      }
}

// =====================================================================
// k_rec helpers
// =====================================================================
__device__ __forceinline__ f16x8 lds_a(const char* astage, int row, int it, int quad) {
  int pos = (it * 4 + quad) ^ (row & 7);  // XOR swizzle on low-3 granule bits
  return *(const f16x8*)(astage + row * 2048 + pos * 16);
}
__device__ __forceinline__ float sigf(float x) { return 1.f / (1.f + __expf(-x)); }
__device__ __forceinline__ float tanhf_fast(float x) { return 1.f - 2.f / (__expf(2.f * x) + 1.f); }

// =====================================================================
// k_rec: 128 WGs x 512 thr. dom=blk&3 (16 batch rows; XCD co-located),
// role=blk>>2: roles 0-15 layer0 (32 h-cols), 16-31 layer1. Per step t:
//   l0: stage q(t); poll f0>=t && f1>=t-6; load h0(t-1) slot (t-1)&7; B1;
//       GEMM(gate-packed B); in-wave EW; store h0(t) slot t&7 (2B agent
//       stores); B3; f0=t+1.
//   l1: poll f0>=t+1 && f1>=t; load h0(t) slot t&7 + h1(t-1) slot (t-1)&1;
//       B1; GEMM; EW; store h1(t) slot t&1; B3; f1=t+1.
// Wave wv covers cols c0+4wv..+3, all 4 gates (B-row = (n15>>2)*512 + col).
// C-frag: lane(quad,n15) = gate n15>>2, col-sub n15&3, rows quad*4+r.
// Owners (n15<4) gather gates via __shfl(lane+4/8/12), hold c-state[4].
// =====================================================================
__global__ __launch_bounds__(512, 2) void k_rec(
    const f16* __restrict__ q16, const f16* __restrict__ w16,
    const float* __restrict__ bsum, f16* __restrict__ h0buf,
    f16* __restrict__ h1buf, float* __restrict__ hlast, unsigned* flg) {
  __shared__ __align__(16) char astage[32768];  // 16 rows x 1024 f16

  const int tid = threadIdx.x, lane = tid & 63, wv = tid >> 6;
  const int n15 = lane & 15, quad = lane >> 4;
  const int dom = blockIdx.x & 3, role = blockIdx.x >> 2;  // XCD co-location
  const int l = role >> 4, cg = role & 15, c0 = cg * 32;
  const int b0 = dom * 16;

  // resident weights, gate-packed: B-row = (n15>>2)*512 + c0 + wv*4 + (n15&3)
  f16x8 wf[32];
  {
    const int brow = (n15 >> 2) * 512 + c0 + wv * 4 + (n15 & 3);
    const f16* wbase = w16 + ((size_t)l * 2048 + (size_t)brow) * 1024 + quad * 8;
#pragma unroll
    for (int it = 0; it < 32; ++it) wf[it] = *(const f16x8*)(wbase + it * 32);
  }
  // owner-lane (n15<4) EW constants/state: col = c0 + wv*4 + (n15&3)
  const int mycol = c0 + wv * 4 + (n15 & 3);
  float bbv[4];
#pragma unroll
  for (int g = 0; g < 4; ++g) bbv[g] = bsum[l * 2048 + g * 512 + mycol];
  float cstate[4] = {0.f, 0.f, 0.f, 0.f};

  // flags: [dom][layer][16 producers], 256B (64-dword) stride (r8-exact)
  unsigned* f0 = flg + (size_t)(dom * 2 + 0) * 1024;
  unsigned* f1 = flg + (size_t)(dom * 2 + 1) * 1024;
  unsigned* myflag = (l ? f1 : f0) + (size_t)cg * 64;
  const int pl = lane & 31;
  const unsigned* pollp = (pl < 16) ? (f0 + pl * 64) : (f1 + (pl - 16) * 64);

  // staging: thread -> row=tid>>5 (16), colgrp=tid&31 (32 x 16 f16 = 32B)
  const int srow = tid >> 5, scg = tid & 31;
  const int g0 = scg * 2;
  char* a_x0 = astage + srow * 2048 + ((g0 ^ (srow & 7)) * 16);
  char* a_x1 = astage + srow * 2048 + (((g0 + 1) ^ (srow & 7)) * 16);
  char* a_h0 = a_x0 + 1024;  // granule +64 (low-3 XOR unaffected)
  char* a_h1 = a_x1 + 1024;
  const size_t soff = (size_t)srow * 512 + scg * 16;  // within a 16x512 slot
  const size_t h0base = (size_t)dom * 8 * 8192;  // 8 slots now
  const size_t h1base = (size_t)dom * 2 * 8192;

  int alive = 1;

  for (int t = 0; t <= 511; ++t) {
    // stage x-part for l0 (immutable q, plain cached loads)
    if (l == 0) {
      const f16* src = q16 + ((size_t)(t * 64 + b0 + srow)) * 512 + scg * 16;
      uint4 v0 = *(const uint4*)src;
      uint4 v1 = *(const uint4*)(src + 8);
      *(uint4*)a_x0 = v0;
      *(uint4*)a_x1 = v1;
    }
    // poll (every wave; r8-style). l0: f0>=t, f1>=t-6 (8-slot WAR).
    // l1: f0>=t+1, f1>=t.
    if ((t >= 1 || l == 1) && alive) {
      const int mytgt = (l == 0) ? ((pl < 16) ? t : (t - 6))
                                 : ((pl < 16) ? (t + 1) : t);
      int iters = 0;
      while (true) {
        int f = (int)LD_AG(pollp);
        if (__all(f >= mytgt)) break;
        if (++iters > POLL_CAP) { alive = 0; break; }
        __builtin_amdgcn_s_sleep(1);
      }
    }
    // stage h-part(s) (agent loads)
    if (l == 0) {
      const u64* hs0 = (const u64*)(h0buf + h0base + (size_t)((t - 1) & 7) * 8192 + soff);
      u64 x0 = LD_AG(hs0);
      u64 x1 = LD_AG(hs0 + 1);
      u64 x2 = LD_AG(hs0 + 2);
      u64 x3 = LD_AG(hs0 + 3);
      ((u64*)a_h0)[0] = x0; ((u64*)a_h0)[1] = x1;
      ((u64*)a_h1)[0] = x2; ((u64*)a_h1)[1] = x3;
    } else {
      const u64* hs0 = (const u64*)(h0buf + h0base + (size_t)(t & 7) * 8192 + soff);  // h0(t)
      u64 x0 = LD_AG(hs0);
      u64 x1 = LD_AG(hs0 + 1);
      u64 x2 = LD_AG(hs0 + 2);
      u64 x3 = LD_AG(hs0 + 3);
      const u64* hs1 = (const u64*)(h1buf + h1base + (size_t)((t - 1) & 1) * 8192 + soff);  // h1(t-1)
      u64 y0 = LD_AG(hs1);
      u64 y1 = LD_AG(hs1 + 1);
      u64 y2 = LD_AG(hs1 + 2);
      u64 y3 = LD_AG(hs1 + 3);
      ((u64*)a_x0)[0] = x0; ((u64*)a_x0)[1] = x1;
      ((u64*)a_x1)[0] = x2; ((u64*)a_x1)[1] = x3;
      ((u64*)a_h0)[0] = y0; ((u64*)a_h0)[1] = y1;
      ((u64*)a_h1)[0] = y2; ((u64*)a_h1)[1] = y3;
    }
    __syncthreads();  // B1: A-tile ready

    // fused GEMM K'=1024, 2 chains; A rows = n15 (16 batch rows)
    f32x4 acc0 = (f32x4){0.f, 0.f, 0.f, 0.f};
    f32x4 acc1 = (f32x4){0.f, 0.f, 0.f, 0.f};
#pragma unroll
    for (int it = 0; it < 32; it += 2) {
      acc0 = MFMA16(lds_a(astage, n15, it, quad), wf[it], acc0);
      acc1 = MFMA16(lds_a(astage, n15, it + 1, quad), wf[it + 1], acc1);
    }
    f32x4 acc = acc0 + acc1;

    // in-wave gate gather: owner lanes n15<4 get f,g,o from lanes +4/+8/+12
    float gfv[4], ggv[4], gov[4];
#pragma unroll
    for (int r = 0; r < 4; ++r) {
      gfv[r] = __shfl(acc[r], lane + 4);
      ggv[r] = __shfl(acc[r], lane + 8);
      gov[r] = __shfl(acc[r], lane + 12);
    }
    // EW + publish (owner lanes): rows quad*4+r, col mycol
    if (n15 < 4) {
#pragma unroll
      for (int r = 0; r < 4; ++r) {
        float gi_ = acc[r] + bbv[0];
        float gf_ = gfv[r] + bbv[1];
        float gg_ = ggv[r] + bbv[2];
        float go_ = gov[r] + bbv[3];
        float c = sigf(gf_) * cstate[r] + sigf(gi_) * tanhf_fast(gg_);
        cstate[r] = c;
        float hv = sigf(go_) * tanhf_fast(c);
        union { f16 h; unsigned short u; } pk;
        pk.h = (f16)hv;
        const int row = quad * 4 + r;
        unsigned short* dst = (l == 0)
            ? (unsigned short*)(h0buf + h0base + (size_t)(t & 7) * 8192 + (size_t)row * 512 + mycol)
            : (unsigned short*)(h1buf + h1base + (size_t)(t & 1) * 8192 + (size_t)row * 512 + mycol);
        ST_AG(dst, pk.u);
        if (l == 1 && t == 511) {
          hlast[(size_t)(b0 + row) * 512 + mycol] = hv;
        }
      }
    }
    __syncthreads();  // B3: stores drained -> flag may publish; astage free
    if (tid == 0) ST_AG(myflag, (unsigned)(t + 1));
  }
}

// =====================================================================
// fc head
// =====================================================================
__global__ __launch_bounds__(512) void k_fc(
    const float* __restrict__ hlast, const float* __restrict__ fc1wT,
    const float* __restrict__ fc1b, const float* __restrict__ fc2w,
    const float* __restrict__ fc2b, float* __restrict__ out) {
  __shared__ float hrow[512];
  __shared__ float red[8];
  const int b = blockIdx.x, tid = threadIdx.x;
  hrow[tid] = hlast[b * 512 + tid];
  __syncthreads();
  float acc = 0.f;
#pragma unroll 8
  for (int k = 0; k < 512; ++k) acc += hrow[k] * fc1wT[k * 512 + tid];
  float h1 = acc + fc1b[tid];
  h1 = h1 > 0.f ? h1 : 0.f;
  float v = h1 * fc2w[tid];
#pragma unroll
  for (int off = 32; off >= 1; off >>= 1) v += __shfl_down(v, off);
  if ((tid & 63) == 0) red[tid >> 6] = v;
  __syncthreads();
  if (tid == 0) {
    float s = 0.f;
#pragma unroll
    for (int w = 0; w < 8; ++w) s += red[w];
    out[b] = s + fc2b[0];
  }
}

// =====================================================================
extern "C" void kernel_launch(void* const* d_in, const int* in_sizes, int n_in,
                              void* d_out, int out_size, void* d_ws, size_t ws_size,
                              hipStream_t stream) {
  if (ws_size < WS_NEEDED) return;  // fail loudly

  const float* x = (const float*)d_in[0];
  const float* theta = (const float*)d_in[1];
  const float* phi = (const float*)d_in[2];
  const float* thn = (const float*)d_in[3];
  const float* phn = (const float*)d_in[4];
  const float* Wih = (const float*)d_in[5];
  const float* Whh = (const float*)d_in[6];
  const float* bih = (const float*)d_in[7];
  const float* bhh = (const float*)d_in[8];
  const float* fc1w = (const float*)d_in[9];
  const float* fc1b = (const float*)d_in[10];
  const float* fc2w = (const float*)d_in[11];
  const float* fc2b = (const float*)d_in[12];

  char* ws = (char*)d_ws;
  f16* q16 = (f16*)(ws + OFF_Q16);
  f16* x16 = (f16*)(ws + OFF_X16);
  f16* w16 = (f16*)(ws + OFF_W16);
  f16* cosT = (f16*)(ws + OFF_COS);
  f16* sinT = (f16*)(ws + OFF_SIN);
  float* bsum = (float*)(ws + OFF_BSUM);
  f16* h0buf = (f16*)(ws + OFF_HBUF);
  f16* h1buf = h0buf + 262144;  // +524,288 B (h0 = 4dom*8slot*8192 f16)
  float* hlast = (float*)(ws + OFF_HLAST);
  float* fc1wT = (float*)(ws + OFF_FC1WT);
  unsigned* flg = (unsigned*)(ws + OFF_FLG);

  k_prep<<<2048, 256, 0, stream>>>(x, theta, phi, thn, phn, Wih, Whh, bih, bhh, fc1w,
                                   x16, w16, cosT, sinT, bsum, fc1wT, h0buf, flg);
  k_quantum<<<dim3(512, 4, 1), 256, 0, stream>>>(x16, cosT, sinT, q16);
  k_rec<<<128, 512, 0, stream>>>(q16, w16, bsum, h0buf, h1buf, hlast, flg);
  k_fc<<<64, 512, 0, stream>>>(hlast, fc1wT, fc1b, fc2w, fc2b, (float*)d_out);
}

// Round 10
// 1861.136 us; speedup vs baseline: 1.1804x; 1.1804x over previous
//
#include <hip/hip_runtime.h>

// EnhancedQuantumInspiredLSTM on MI355X (gfx950).
// Round-18 = the PROVEN r8 baseline (1853us) with ONE surgical change:
// h0 slots 4 -> 8 and l0's WAR guard f1>=t-2 -> f1>=t-6.
// Theory: with 4 slots the WAR guard serializes the two layers (l0 step t
// waits for l1 step t-2, which waits for l0 step t-1) -> period = SUM of
// both layers' chains (2 x ~1.7us = 3.4us measured). Slack 6 lets l1 trail
// l0 by ~1 step with both streaming concurrently -> period = max(chain).
// Safety: writing h0 slot t&7 overwrites h0(t-8); l1 read it at step t-8,
// guaranteed done by f1 >= t-7 (we use t-6, 1 conservative). l0 peers are
// lockstep within 1 step via f0 -> their reads are 7 slots behind the write.
// h1 double-buffer + f1>=t poll unchanged (self-contained, proven).
// Bounded polls with free-run latch = hang insurance only (inert when ok).
// Everything else byte-identical to r8: mapping dom=blk>>5, flags at 64-dword
// stride, gbuf EW, B1/B2/B3, agent-scope loads/stores.

typedef _Float16 f16;
typedef _Float16 f16x8 __attribute__((ext_vector_type(8)));
typedef float f32x4 __attribute__((ext_vector_type(4)));
typedef unsigned long long u64;

#define MFMA16(a, b, c) __builtin_amdgcn_mfma_f32_16x16x32_f16((a), (b), (c), 0, 0, 0)
#define LD_AG(p) __hip_atomic_load((p), __ATOMIC_RELAXED, __HIP_MEMORY_SCOPE_AGENT)
#define ST_AG(p, v) __hip_atomic_store((p), (v), __ATOMIC_RELAXED, __HIP_MEMORY_SCOPE_AGENT)
#define POLL_CAP (1 << 20)

// ---- workspace layout (bytes) ----
#define OFF_Q16 0UL           // 32768*512*2 = 33,554,432  rows = s*64+b
#define OFF_X16 33554432UL    // 8,388,608
#define OFF_W16 41943040UL    // 2*2048*1024*2 = 8,388,608  [l][row][k']
#define OFF_COS 50331648UL    // 131,072 (transposed [h][i])
#define OFF_SIN 50462720UL    // 131,072
#define OFF_BSUM 50593792UL   // 16,384
#define OFF_HBUF 50610176UL   // h0 4dom*8slot*16*512*2=524,288 ; h1 4*2*16*512*2=131,072
#define OFF_HLAST 51265536UL  // 131,072
#define OFF_FC1WT 51396608UL  // 1,048,576
#define OFF_FLG 52445184UL    // 128 flags * 256B = 32,768
#define WS_NEEDED 52477952UL

// =====================================================================
// prep
// =====================================================================
__global__ __launch_bounds__(256) void k_prep(
    const float* __restrict__ x, const float* __restrict__ theta,
    const float* __restrict__ phi, const float* __restrict__ thn,
    const float* __restrict__ phn, const float* __restrict__ Wih,
    const float* __restrict__ Whh, const float* __restrict__ bih,
    const float* __restrict__ bhh, const float* __restrict__ fc1w,
    f16* __restrict__ x16, f16* __restrict__ w16, f16* __restrict__ cosT,
    f16* __restrict__ sinT, float* __restrict__ bsum, float* __restrict__ fc1wT,
    f16* __restrict__ hbuf, unsigned* __restrict__ flg) {
  const int T1 = 4194304;        // x16
  const int T2 = T1 + 4194304;   // w16 combined [l][2048][1024]
  const int T3 = T2 + 65536;     // cos/sin
  const int T4 = T3 + 262144;    // fc1wT
  const int T5 = T4 + 4096;      // bsum
  const int T6 = T5 + 327680;    // zero hbuf (h0 262144 + h1 65536 f16)
  const int T7 = T6 + 8192;      // zero flags (dwords)
  for (int idx = blockIdx.x * 256 + threadIdx.x; idx < T7; idx += gridDim.x * 256) {
    if (idx < T1) {
      int s = idx >> 13, rem = idx & 8191, b = rem >> 7, i = rem & 127;
      x16[idx] = (f16)x[b * 65536 + s * 128 + i];
    } else if (idx < T2) {
      int j = idx - T1;
      int l = j >> 21, rem = j & 2097151, r = rem >> 10, k = rem & 1023;
      float v = (k < 512) ? Wih[((size_t)l * 2048 + r) * 512 + k]
                          : Whh[((size_t)l * 2048 + r) * 512 + (k - 512)];
      w16[(size_t)l * 2097152 + (size_t)r * 1024 + k] = (f16)v;
    } else if (idx < T3) {
      int e = idx - T2;
      int i = e >> 9, h = e & 511;
      cosT[h * 128 + i] = (f16)cosf(theta[e] + thn[e]);
      sinT[h * 128 + i] = (f16)sinf(phi[e] + phn[e]);
    } else if (idx < T4) {
      int e = idx - T3;
      int n = e >> 9, k = e & 511;
      fc1wT[k * 512 + n] = fc1w[e];
    } else if (idx < T5) {
      int e = idx - T4;
      bsum[e] = bih[e] + bhh[e];
    } else if (idx < T6) {
      hbuf[idx - T5] = (f16)0.f;
    } else {
      flg[idx - T6] = 0u;
    }
  }
}

// =====================================================================
// quantum: q16[(s*64+b)][h] = |x.(cos+isin)|, fp16 MFMA (unchanged)
// =====================================================================
__global__ __launch_bounds__(256) void k_quantum(
    const f16* __restrict__ x16, const f16* __restrict__ cosT,
    const f16* __restrict__ sinT, f16* __restrict__ q16) {
  __shared__ __align__(16) f16 a_lds[64 * 136];
  const int tid = threadIdx.x;
  const int r0 = blockIdx.x * 64, h0 = blockIdx.y * 128;
#pragma unroll
  for (int g = 0; g < 4; ++g) {
    int G = g * 256 + tid, row = G >> 4, col = G & 15;
    *(uint4*)((char*)a_lds + row * 272 + col * 16) =
        *(const uint4*)(x16 + (size_t)(r0 + row) * 128 + col * 8);
  }
  __syncthreads();
  const int wv = tid >> 6, lane = tid & 63, n15 = lane & 15, quad = lane >> 4;
  const int nb = h0 + wv * 32;
  f32x4 ac[4][2], as_[4][2];
#pragma unroll
  for (int mt = 0; mt < 4; ++mt)
#pragma unroll
    for (int nt = 0; nt < 2; ++nt) {
      ac[mt][nt] = (f32x4){0.f, 0.f, 0.f, 0.f};
      as_[mt][nt] = (f32x4){0.f, 0.f, 0.f, 0.f};
    }
#pragma unroll
  for (int it = 0; it < 4; ++it) {
    f16x8 a[4];
#pragma unroll
    for (int mt = 0; mt < 4; ++mt)
      a[mt] = *(const f16x8*)((const char*)a_lds + (mt * 16 + n15) * 272 + it * 64 + quad * 16);
#pragma unroll
    for (int nt = 0; nt < 2; ++nt) {
      const f16x8 bc = *(const f16x8*)(cosT + (size_t)(nb + nt * 16 + n15) * 128 + it * 32 + quad * 8);
      const f16x8 bs = *(const f16x8*)(sinT + (size_t)(nb + nt * 16 + n15) * 128 + it * 32 + quad * 8);
#pragma unroll
      for (int mt = 0; mt < 4; ++mt) {
        ac[mt][nt] = MFMA16(a[mt], bc, ac[mt][nt]);
        as_[mt][nt] = MFMA16(a[mt], bs, as_[mt][nt]);
      }
    }
  }
#pragma unroll
  for (int mt = 0; mt < 4; ++mt)
#pragma unroll
    for (int nt = 0; nt < 2; ++nt)
#pragma unroll
      for (int r = 0; r < 4; ++r) {
        int row = r0 + mt * 16 + quad * 4 + r;
        int col = nb + nt * 16 + n15;
        float re = ac[mt][nt][r], im = as_[mt][nt][r];
        q16[(size_t)row * 512 + col] = (f16)sqrtf(re * re + im * im);
      }
}

// =====================================================================
// k_rec helpers
// =====================================================================
__device__ __forceinline__ f16x8 lds_a(const char* astage, int row, int it, int quad) {
  int pos = (it * 4 + quad) ^ (row & 7);  // XOR swizzle on low-3 granule bits
  return *(const f16x8*)(astage + row * 2048 + pos * 16);
}
__device__ __forceinline__ float sigf(float x) { return 1.f / (1.f + __expf(-x)); }
__device__ __forceinline__ float tanhf_fast(float x) { return 1.f - 2.f / (__expf(2.f * x) + 1.f); }

// =====================================================================
// k_rec: 128 WGs x 512 thr. dom=blockIdx>>5 (16 batch rows), role=blockIdx&31:
// roles 0-15 layer0 (32 h-cols each), 16-31 layer1. Per step t:
//   l0: A=[q(t)|h0(t-1)], publish h0(t) slot t&7, flag f0=t+1
//   l1: A=[h0(t)|h1(t-1)], publish h1(t) slot t&1, flag f1=t+1
// Polls: l0: f0>=t && f1>=t-6 (8-slot WAR); l1: f0>=t+1 && f1>=t.
// =====================================================================
__global__ __launch_bounds__(512, 2) void k_rec(
    const f16* __restrict__ q16, const f16* __restrict__ w16,
    const float* __restrict__ bsum, f16* __restrict__ h0buf,
    f16* __restrict__ h1buf, float* __restrict__ hlast, unsigned* flg) {
  __shared__ __align__(16) char astage[32768];  // 16 rows x 1024 f16
  __shared__ float gbuf[16 * 132];

  const int tid = threadIdx.x, lane = tid & 63, wv = tid >> 6;
  const int n15 = lane & 15, quad = lane >> 4;
  const int qg = wv >> 1, ch = wv & 1;  // gate, col-half for this wave
  const int dom = blockIdx.x >> 5, role = blockIdx.x & 31;
  const int l = role >> 4, c0 = (role & 15) * 32;
  const int b0 = dom * 16;

  // resident combined weights: rows qg*512 + c0 + ch*16 + n15, K'=1024
  f16x8 wf[32];
  {
    const f16* wbase = w16 + ((size_t)l * 2048 + (size_t)(qg * 512 + c0 + ch * 16 + n15)) * 1024 + quad * 8;
#pragma unroll
    for (int it = 0; it < 32; ++it) wf[it] = *(const f16x8*)(wbase + it * 32);
  }
  float bb[4][2];  // used by ew threads (tid<256): b=tid>>4, jc=(tid&15)*2
#pragma unroll
  for (int g = 0; g < 4; ++g)
#pragma unroll
    for (int j = 0; j < 2; ++j)
      bb[g][j] = bsum[l * 2048 + g * 512 + c0 + (tid & 15) * 2 + j];
  float cs0 = 0.f, cs1 = 0.f;

  // flags: [dom][layer][16 producers], 256B (64-dword) stride
  unsigned* f0 = flg + (size_t)(dom * 2 + 0) * 1024;
  unsigned* f1 = flg + (size_t)(dom * 2 + 1) * 1024;
  unsigned* myflag = (l ? f1 : f0) + (size_t)(role & 15) * 64;
  const int pl = lane & 31;
  const unsigned* pollp = (pl < 16) ? (f0 + pl * 64) : (f1 + (pl - 16) * 64);

  // staging: thread -> row=tid>>5 (16), colgrp=tid&31 (32 x 16 f16 = 32B)
  const int srow = tid >> 5, scg = tid & 31;
  const int g0 = scg * 2;
  char* a_x0 = astage + srow * 2048 + ((g0 ^ (srow & 7)) * 16);
  char* a_x1 = astage + srow * 2048 + (((g0 + 1) ^ (srow & 7)) * 16);
  char* a_h0 = a_x0 + 1024;  // granule +64 (low-3 XOR unaffected)
  char* a_h1 = a_x1 + 1024;
  const size_t soff = (size_t)srow * 512 + scg * 16;  // within a 16x512 slot
  const size_t h0base = (size_t)dom * 8 * 8192;       // 8 slots
  const size_t h1base = (size_t)dom * 2 * 8192;

  int alive = 1;  // wave-uniform; latched 0 on poll timeout (free-run mode)

  for (int t = 0; t <= 511; ++t) {
    // stage x-part for l0 (immutable q, plain cached loads)
    if (l == 0) {
      const f16* src = q16 + ((size_t)(t * 64 + b0 + srow)) * 512 + scg * 16;
      uint4 v0 = *(const uint4*)src;
      uint4 v1 = *(const uint4*)(src + 8);
      *(uint4*)a_x0 = v0;
      *(uint4*)a_x1 = v1;
    }
    // poll (every wave; one lane-parallel load per iteration; bounded)
    // l0: f0>=t (peers at t-1 done), f1>=t-6 (WAR: l1 done reading slot t&7)
    // l1: f0>=t+1 (h0(t) published), f1>=t (peers' h1(t-1) published)
    if ((t >= 1 || l == 1) && alive) {
      const int mytgt = (l == 0) ? ((pl < 16) ? t : (t - 6))
                                 : ((pl < 16) ? (t + 1) : t);
      int iters = 0;
      while (true) {
        int f = (int)LD_AG(pollp);
        if (__all(f >= mytgt)) break;
        if (++iters > POLL_CAP) { alive = 0; break; }
        __builtin_amdgcn_s_sleep(1);
      }
    }
    // stage h-part(s) (AGENT coherent loads)
    if (l == 0) {
      const u64* hs0 = (const u64*)(h0buf + h0base + (size_t)((t - 1) & 7) * 8192 + soff);
      u64 x0 = LD_AG(hs0);
      u64 x1 = LD_AG(hs0 + 1);
      u64 x2 = LD_AG(hs0 + 2);
      u64 x3 = LD_AG(hs0 + 3);
      ((u64*)a_h0)[0] = x0; ((u64*)a_h0)[1] = x1;
      ((u64*)a_h1)[0] = x2; ((u64*)a_h1)[1] = x3;
    } else {
      const u64* hs0 = (const u64*)(h0buf + h0base + (size_t)(t & 7) * 8192 + soff);  // h0(t)
      u64 x0 = LD_AG(hs0);
      u64 x1 = LD_AG(hs0 + 1);
      u64 x2 = LD_AG(hs0 + 2);
      u64 x3 = LD_AG(hs0 + 3);
      const u64* hs1 = (const u64*)(h1buf + h1base + (size_t)((t - 1) & 1) * 8192 + soff);  // h1(t-1)
      u64 y0 = LD_AG(hs1);
      u64 y1 = LD_AG(hs1 + 1);
      u64 y2 = LD_AG(hs1 + 2);
      u64 y3 = LD_AG(hs1 + 3);
      ((u64*)a_x0)[0] = x0; ((u64*)a_x0)[1] = x1;
      ((u64*)a_x1)[0] = x2; ((u64*)a_x1)[1] = x3;
      ((u64*)a_h0)[0] = y0; ((u64*)a_h0)[1] = y1;
      ((u64*)a_h1)[0] = y2; ((u64*)a_h1)[1] = y3;
    }
    __syncthreads();  // B1: A-tile ready

    // fused GEMM K'=1024
    f32x4 acc = (f32x4){0.f, 0.f, 0.f, 0.f};
#pragma unroll
    for (int it = 0; it < 32; ++it)
      acc = MFMA16(lds_a(astage, n15, it, quad), wf[it], acc);
#pragma unroll
    for (int r = 0; r < 4; ++r)
      gbuf[(quad * 4 + r) * 132 + qg * 33 + ch * 16 + n15] = acc[r];
    __syncthreads();  // B2: gbuf ready (astage reads done)

    // elementwise + publish (threads 0-255: b=tid>>4, 2 cols)
    if (tid < 256) {
      const int b = tid >> 4, jc = (tid & 15) * 2;
      float hv[2];
#pragma unroll
      for (int j = 0; j < 2; ++j) {
        const float* gb = gbuf + b * 132 + jc + j;
        float gi = gb[0] + bb[0][j];
        float gf = gb[33] + bb[1][j];
        float gg = gb[66] + bb[2][j];
        float go = gb[99] + bb[3][j];
        float cprev = j ? cs1 : cs0;
        float c = sigf(gf) * cprev + sigf(gi) * tanhf_fast(gg);
        if (j) cs1 = c; else cs0 = c;
        hv[j] = sigf(go) * tanhf_fast(c);
      }
      union { f16 h2[2]; unsigned u; } pk;
      pk.h2[0] = (f16)hv[0];
      pk.h2[1] = (f16)hv[1];
      f16* dst = (l == 0)
          ? h0buf + h0base + (size_t)(t & 7) * 8192 + (size_t)b * 512 + c0 + jc
          : h1buf + h1base + (size_t)(t & 1) * 8192 + (size_t)b * 512 + c0 + jc;
      ST_AG((unsigned*)dst, pk.u);
      if (l == 1 && t == 511) {
        hlast[(size_t)(b0 + b) * 512 + c0 + jc] = hv[0];
        hlast[(size_t)(b0 + b) * 512 + c0 + jc + 1] = hv[1];
      }
    }
    __syncthreads();  // B3: vmcnt drained -> h stores visible
    if (tid == 0) ST_AG(myflag, (unsigned)(t + 1));
  }
}

// =====================================================================
// fc head
// =====================================================================
__global__ __launch_bounds__(512) void k_fc(
    const float* __restrict__ hlast, const float* __restrict__ fc1wT,
    const float* __restrict__ fc1b, const float* __restrict__ fc2w,
    const float* __restrict__ fc2b, float* __restrict__ out) {
  __shared__ float hrow[512];
  __shared__ float red[8];
  const int b = blockIdx.x, tid = threadIdx.x;
  hrow[tid] = hlast[b * 512 + tid];
  __syncthreads();
  float acc = 0.f;
#pragma unroll 8
  for (int k = 0; k < 512; ++k) acc += hrow[k] * fc1wT[k * 512 + tid];
  float h1 = acc + fc1b[tid];
  h1 = h1 > 0.f ? h1 : 0.f;
  float v = h1 * fc2w[tid];
#pragma unroll
  for (int off = 32; off >= 1; off >>= 1) v += __shfl_down(v, off);
  if ((tid & 63) == 0) red[tid >> 6] = v;
  __syncthreads();
  if (tid == 0) {
    float s = 0.f;
#pragma unroll
    for (int w = 0; w < 8; ++w) s += red[w];
    out[b] = s + fc2b[0];
  }
}

// =====================================================================
extern "C" void kernel_launch(void* const* d_in, const int* in_sizes, int n_in,
                              void* d_out, int out_size, void* d_ws, size_t ws_size,
                              hipStream_t stream) {
  if (ws_size < WS_NEEDED) return;  // fail loudly

  const float* x = (const float*)d_in[0];
  const float* theta = (const float*)d_in[1];
  const float* phi = (const float*)d_in[2];
  const float* thn = (const float*)d_in[3];
  const float* phn = (const float*)d_in[4];
  const float* Wih = (const float*)d_in[5];
  const float* Whh = (const float*)d_in[6];
  const float* bih = (const float*)d_in[7];
  const float* bhh = (const float*)d_in[8];
  const float* fc1w = (const float*)d_in[9];
  const float* fc1b = (const float*)d_in[10];
  const float* fc2w = (const float*)d_in[11];
  const float* fc2b = (const float*)d_in[12];

  char* ws = (char*)d_ws;
  f16* q16 = (f16*)(ws + OFF_Q16);
  f16* x16 = (f16*)(ws + OFF_X16);
  f16* w16 = (f16*)(ws + OFF_W16);
  f16* cosT = (f16*)(ws + OFF_COS);
  f16* sinT = (f16*)(ws + OFF_SIN);
  float* bsum = (float*)(ws + OFF_BSUM);
  f16* h0buf = (f16*)(ws + OFF_HBUF);
  f16* h1buf = h0buf + 262144;  // +524,288 B (h0 = 4dom*8slot*8192 f16)
  float* hlast = (float*)(ws + OFF_HLAST);
  float* fc1wT = (float*)(ws + OFF_FC1WT);
  unsigned* flg = (unsigned*)(ws + OFF_FLG);

  k_prep<<<2048, 256, 0, stream>>>(x, theta, phi, thn, phn, Wih, Whh, bih, bhh, fc1w,
                                   x16, w16, cosT, sinT, bsum, fc1wT, h0buf, flg);
  k_quantum<<<dim3(512, 4, 1), 256, 0, stream>>>(x16, cosT, sinT, q16);
  k_rec<<<128, 512, 0, stream>>>(q16, w16, bsum, h0buf, h1buf, hlast, flg);
  k_fc<<<64, 512, 0, stream>>>(hlast, fc1wT, fc1b, fc2w, fc2b, (float*)d_out);
}